// Round 4
// baseline (578.571 us; speedup 1.0000x reference)
//
#include <hip/hip_runtime.h>
#include <stdint.h>

#define BATCH 4096
#define DIN 1024
#define DOUT 1024
#define NC 11          // GRID_SIZE + SPLINE_ORDER
#define KD 12288       // DIN * (1 + NC)
#define NKNOTS 15      // GRID_SIZE + 2*SPLINE_ORDER + 1

typedef __bf16 bf16x8 __attribute__((ext_vector_type(8)));
typedef float f32x4 __attribute__((ext_vector_type(4)));

__device__ __forceinline__ unsigned short f2bf(float f) {
    unsigned int u = __float_as_uint(f);
    unsigned int r = (u + 0x7FFFu + ((u >> 16) & 1u)) >> 16;
    return (unsigned short)r;
}

// ---------------------------------------------------------------------------
// Build A[b, :] = [ silu(x[b,:]) (1024) | bsplines(silu(x[b,:])) (1024*11) ] in bf16
// ---------------------------------------------------------------------------
__global__ __launch_bounds__(256) void build_A(
    const float* __restrict__ x, const float* __restrict__ grid,
    unsigned short* __restrict__ A) {
    __shared__ __align__(16) unsigned short lbs[256 * NC];
    const int tid = threadIdx.x;
    const int b  = blockIdx.x >> 2;
    const int i0 = (blockIdx.x & 3) * 256;
    const int i  = i0 + tid;

    float g[NKNOTS];
#pragma unroll
    for (int j = 0; j < NKNOTS; ++j) g[j] = grid[j];

    const float xv = x[(size_t)b * DIN + i];
    const float s  = xv / (1.f + __expf(-xv));   // silu

    float bs[14];
#pragma unroll
    for (int c = 0; c < 14; ++c) bs[c] = (s >= g[c] && s < g[c + 1]) ? 1.f : 0.f;
#pragma unroll
    for (int k = 1; k <= 3; ++k) {
        const float inv = (k == 1) ? 4.f : (k == 2) ? 2.f : (4.f / 3.f);
#pragma unroll
        for (int c = 0; c < 14 - k; ++c) {
            float left  = (s - g[c]) * inv;
            float right = (g[c + k + 1] - s) * inv;
            bs[c] = left * bs[c] + right * bs[c + 1];
        }
    }

    A[(size_t)b * KD + i] = f2bf(s);
#pragma unroll
    for (int c = 0; c < NC; ++c) lbs[tid * NC + c] = f2bf(bs[c]);
    __syncthreads();

    const uint4* src = (const uint4*)lbs;
    uint4* dst = (uint4*)(A + (size_t)b * KD + DIN + (size_t)i0 * NC);
    for (int j = tid; j < 352; j += 256) dst[j] = src[j];
}

// ---------------------------------------------------------------------------
// Build W[o, :] = [ base_w[o,:] | spline_w[o,:,:]*scaler[o,:] ] in bf16
// ---------------------------------------------------------------------------
__global__ __launch_bounds__(256) void build_W(
    const float* __restrict__ base_w, const float* __restrict__ spline_w,
    const float* __restrict__ scaler, unsigned short* __restrict__ W) {
    __shared__ __align__(16) unsigned short lw[256 * NC];
    const int tid = threadIdx.x;
    const int o  = blockIdx.x >> 2;
    const int i0 = (blockIdx.x & 3) * 256;
    const int i  = i0 + tid;
    const size_t oi = (size_t)o * DIN + i;

    const float sc = scaler[oi];
    W[(size_t)o * KD + i] = f2bf(base_w[oi]);
    const float* sw = spline_w + oi * NC;
#pragma unroll
    for (int c = 0; c < NC; ++c) lw[tid * NC + c] = f2bf(sw[c] * sc);
    __syncthreads();

    const uint4* src = (const uint4*)lw;
    uint4* dst = (uint4*)(W + (size_t)o * KD + DIN + (size_t)i0 * NC);
    for (int j = tid; j < 352; j += 256) dst[j] = src[j];
}

// ---------------------------------------------------------------------------
// GEMM: C[4096,1024] = A[4096,12288](bf16) @ W[1024,12288]^T(bf16), f32 out.
// 128x128 tile, BK=64, 512 threads (8 waves, 2x4).
// A: 4-deep LDS ring (64KB), T2 swizzle, global_load_lds staging.
// B(W): global->VGPR direct (L2-resident 3MB panel per XCD), pipelined one
// K-tile ahead in two named register sets (unroll-2). Counted vmcnt, raw
// s_barrier once per K-step; setprio around MFMA cluster.
// ---------------------------------------------------------------------------
#define BM 128
#define BN 128
#define BK 64
#define KTILES (KD / BK)   // 192
#define DEPTH 4

__global__ __launch_bounds__(512) void gemm_kan(
    const unsigned short* __restrict__ A,
    const unsigned short* __restrict__ W,
    float* __restrict__ C) {
    __shared__ unsigned short As[DEPTH][BM * BK];   // 4 x 16KB = 64KB

    const int tid  = threadIdx.x;
    const int wave = tid >> 6;
    const int lane = tid & 63;
    const int m0 = (blockIdx.x >> 3) * BM;
    const int n0 = (blockIdx.x & 7) * BN;       // bid%8 == XCD: W panel stays in L2
    const int wm = wave >> 2;                   // 0..1
    const int wn = wave & 3;                    // 0..3

    // A staging: linear LDS dest (lane*16B); global source col pre-swizzled so
    // LDS[row][c'] holds global col c = c' ^ ((row&7)<<4)  (T2, rule #21)
    const int srow = lane >> 3;
    const int scol = 8 * ((lane & 7) ^ (lane >> 3));

    f32x4 acc[4][2];
#pragma unroll
    for (int a = 0; a < 4; ++a)
#pragma unroll
        for (int b = 0; b < 2; ++b) acc[a][b] = (f32x4){0.f, 0.f, 0.f, 0.f};

    auto stage = [&](int kt) {
        const int buf = kt & (DEPTH - 1);
        const int kk = kt * BK + scol;
#pragma unroll
        for (int c = 0; c < 2; ++c) {
            const int chunk = wave * 2 + c;     // 0..15
            const unsigned short* ga = A + (size_t)(m0 + chunk * 8 + srow) * KD + kk;
            __builtin_amdgcn_global_load_lds(
                (const __attribute__((address_space(1))) unsigned int*)ga,
                (__attribute__((address_space(3))) unsigned int*)&As[buf][chunk * 512],
                16, 0, 0);
        }
    };

    // B fragment base: row = n0 + wn*32 + fn*16 + (lane&15), col = (lane>>4)*8
    const unsigned short* Wb = W + (size_t)(n0 + wn * 32 + (lane & 15)) * KD + (lane >> 4) * 8;

#define LOADB(dst, kt)                                                         \
    {                                                                          \
        _Pragma("unroll")                                                      \
        for (int fn = 0; fn < 2; ++fn)                                         \
            _Pragma("unroll")                                                  \
            for (int ks = 0; ks < 2; ++ks)                                     \
                dst[fn][ks] = *(const bf16x8*)(Wb + (size_t)fn * 16 * KD +     \
                                               (kt) * BK + ks * 32);           \
    }

    // prologue: 3 ring slots of A (6 loads) + B tile 0 (4 loads)
    stage(0);
    stage(1);
    stage(2);
    bf16x8 b0[2][2], b1[2][2];
    LOADB(b0, 0);

    const int arow = wm * 64 + (lane & 15);
    const int xr   = lane & 7;
    const int kcol = lane >> 4;

#define PHASE(KT, BC, BNX)                                                     \
    {                                                                          \
        const int kt_ = (KT);                                                  \
        if (kt_ < KTILES - 3) asm volatile("s_waitcnt vmcnt(6)" ::: "memory"); \
        else                  asm volatile("s_waitcnt vmcnt(0)" ::: "memory"); \
        __builtin_amdgcn_sched_barrier(0);                                     \
        __builtin_amdgcn_s_barrier();                                          \
        __builtin_amdgcn_sched_barrier(0);                                     \
        if (kt_ + 3 < KTILES) stage(kt_ + 3);                                  \
        if (kt_ + 1 < KTILES) LOADB(BNX, kt_ + 1);                             \
        __builtin_amdgcn_sched_barrier(0);                                     \
        __builtin_amdgcn_s_setprio(1);                                         \
        const int cur_ = kt_ & (DEPTH - 1);                                    \
        _Pragma("unroll")                                                      \
        for (int ks = 0; ks < 2; ++ks) {                                       \
            const int slot = ((ks * 4 + kcol) ^ xr) * 8;                       \
            bf16x8 af[4];                                                      \
            _Pragma("unroll")                                                  \
            for (int fm = 0; fm < 4; ++fm)                                     \
                af[fm] = *(const bf16x8*)&As[cur_][(arow + fm * 16) * BK + slot]; \
            _Pragma("unroll")                                                  \
            for (int fm = 0; fm < 4; ++fm)                                     \
                _Pragma("unroll")                                              \
                for (int fn = 0; fn < 2; ++fn)                                 \
                    acc[fm][fn] = __builtin_amdgcn_mfma_f32_16x16x32_bf16(     \
                        af[fm], BC[fn][ks], acc[fm][fn], 0, 0, 0);             \
        }                                                                      \
        __builtin_amdgcn_s_setprio(0);                                         \
    }

    for (int kt = 0; kt < KTILES; kt += 2) {
        PHASE(kt,     b0, b1);
        PHASE(kt + 1, b1, b0);
    }

    // epilogue: C/D layout col=lane&15, row=(lane>>4)*4+reg
    const int crow = (lane >> 4) * 4;
    const int ccol = lane & 15;
#pragma unroll
    for (int fm = 0; fm < 4; ++fm)
#pragma unroll
        for (int fn = 0; fn < 2; ++fn) {
            const int row = m0 + wm * 64 + fm * 16 + crow;
            const int col = n0 + wn * 32 + fn * 16 + ccol;
#pragma unroll
            for (int r = 0; r < 4; ++r)
                C[(size_t)(row + r) * DOUT + col] = acc[fm][fn][r];
        }
#undef PHASE
#undef LOADB
}

// ---------------------------------------------------------------------------
extern "C" void kernel_launch(void* const* d_in, const int* in_sizes, int n_in,
                              void* d_out, int out_size, void* d_ws, size_t ws_size,
                              hipStream_t stream) {
    const float* x        = (const float*)d_in[0];
    const float* base_w   = (const float*)d_in[1];
    const float* spline_w = (const float*)d_in[2];
    const float* scaler   = (const float*)d_in[3];
    const float* grid     = (const float*)d_in[4];
    float* out = (float*)d_out;

    char* ws = (char*)d_ws;
    unsigned short* Abf = (unsigned short*)ws;                         // 100,663,296 B
    unsigned short* Wbf = (unsigned short*)(ws + 100663296);           //  25,165,824 B
    float* xtmp = (float*)(ws + 100663296 + 25165824);                 //  16,777,216 B

    for (int layer = 0; layer < 2; ++layer) {
        const float* xin = (layer == 0) ? x : xtmp;
        float* xout      = (layer == 0) ? xtmp : out;
        build_W<<<4096, 256, 0, stream>>>(base_w + (size_t)layer * DOUT * DIN,
                                          spline_w + (size_t)layer * DOUT * DIN * NC,
                                          scaler + (size_t)layer * DOUT * DIN, Wbf);
        build_A<<<16384, 256, 0, stream>>>(xin, grid, Abf);
        gemm_kan<<<256, 512, 0, stream>>>(Abf, Wbf, xout);
    }
}

// Round 5
// 357.279 us; speedup vs baseline: 1.6194x; 1.6194x over previous
//
#include <hip/hip_runtime.h>
#include <stdint.h>

#define BATCH 4096
#define DIN 1024
#define DOUT 1024
#define NC 11          // GRID_SIZE + SPLINE_ORDER
#define KD 12288       // DIN * (1 + NC)
#define NKNOTS 15      // GRID_SIZE + 2*SPLINE_ORDER + 1

typedef __bf16 bf16x8 __attribute__((ext_vector_type(8)));
typedef float f32x4 __attribute__((ext_vector_type(4)));

__device__ __forceinline__ unsigned short f2bf(float f) {
    unsigned int u = __float_as_uint(f);
    unsigned int r = (u + 0x7FFFu + ((u >> 16) & 1u)) >> 16;
    return (unsigned short)r;
}

// ---------------------------------------------------------------------------
// Build A[b, :] = [ silu(x[b,:]) (1024) | bsplines(silu(x[b,:])) (1024*11) ] in bf16
// ---------------------------------------------------------------------------
__global__ __launch_bounds__(256) void build_A(
    const float* __restrict__ x, const float* __restrict__ grid,
    unsigned short* __restrict__ A) {
    __shared__ __align__(16) unsigned short lbs[256 * NC];
    const int tid = threadIdx.x;
    const int b  = blockIdx.x >> 2;
    const int i0 = (blockIdx.x & 3) * 256;
    const int i  = i0 + tid;

    float g[NKNOTS];
#pragma unroll
    for (int j = 0; j < NKNOTS; ++j) g[j] = grid[j];

    const float xv = x[(size_t)b * DIN + i];
    const float s  = xv / (1.f + __expf(-xv));   // silu

    float bs[14];
#pragma unroll
    for (int c = 0; c < 14; ++c) bs[c] = (s >= g[c] && s < g[c + 1]) ? 1.f : 0.f;
#pragma unroll
    for (int k = 1; k <= 3; ++k) {
        const float inv = (k == 1) ? 4.f : (k == 2) ? 2.f : (4.f / 3.f);
#pragma unroll
        for (int c = 0; c < 14 - k; ++c) {
            float left  = (s - g[c]) * inv;
            float right = (g[c + k + 1] - s) * inv;
            bs[c] = left * bs[c] + right * bs[c + 1];
        }
    }

    A[(size_t)b * KD + i] = f2bf(s);
#pragma unroll
    for (int c = 0; c < NC; ++c) lbs[tid * NC + c] = f2bf(bs[c]);
    __syncthreads();

    const uint4* src = (const uint4*)lbs;
    uint4* dst = (uint4*)(A + (size_t)b * KD + DIN + (size_t)i0 * NC);
    for (int j = tid; j < 352; j += 256) dst[j] = src[j];
}

// ---------------------------------------------------------------------------
// Build W[o, :] = [ base_w[o,:] | spline_w[o,:,:]*scaler[o,:] ] in bf16
// ---------------------------------------------------------------------------
__global__ __launch_bounds__(256) void build_W(
    const float* __restrict__ base_w, const float* __restrict__ spline_w,
    const float* __restrict__ scaler, unsigned short* __restrict__ W) {
    __shared__ __align__(16) unsigned short lw[256 * NC];
    const int tid = threadIdx.x;
    const int o  = blockIdx.x >> 2;
    const int i0 = (blockIdx.x & 3) * 256;
    const int i  = i0 + tid;
    const size_t oi = (size_t)o * DIN + i;

    const float sc = scaler[oi];
    W[(size_t)o * KD + i] = f2bf(base_w[oi]);
    const float* sw = spline_w + oi * NC;
#pragma unroll
    for (int c = 0; c < NC; ++c) lw[tid * NC + c] = f2bf(sw[c] * sc);
    __syncthreads();

    const uint4* src = (const uint4*)lw;
    uint4* dst = (uint4*)(W + (size_t)o * KD + DIN + (size_t)i0 * NC);
    for (int j = tid; j < 352; j += 256) dst[j] = src[j];
}

// ---------------------------------------------------------------------------
// GEMM (split-K=2): C = A[4096,12288] @ W[1024,12288]^T, f32 out.
// 128x128 tile, BK=64, 256 threads (4 waves, 2x2 grid of 64x64 wave tiles,
// acc 4x4 -> 32 MFMA/wave/K-step). Grid 512 = 2 independent blocks/CU so
// barrier stalls of one block hide under the other's compute.
// A,W both staged via global_load_lds, T2 XOR-swizzle, DEPTH=2 dbuf (64KB).
// ksplit 0 writes C0 directly; ksplit 1 writes partial P (reduce adds later).
// ---------------------------------------------------------------------------
#define BM 128
#define BN 128
#define BK 64
#define KSPLIT 2
#define KT_PER (KD / BK / KSPLIT)   // 96

__global__ __launch_bounds__(256, 2) void gemm_kan(
    const unsigned short* __restrict__ A,
    const unsigned short* __restrict__ W,
    float* __restrict__ C0, float* __restrict__ P1) {
    __shared__ unsigned short As[2][BM * BK];   // 2 x 16KB
    __shared__ unsigned short Bs[2][BN * BK];   // 2 x 16KB (64KB total)

    const int tid  = threadIdx.x;
    const int wave = tid >> 6;
    const int lane = tid & 63;
    const int n0  = (blockIdx.x & 7) * BN;        // bid%8 == XCD: W panel L2-local
    const int ksp = (blockIdx.x >> 3) & 1;
    const int m0  = (blockIdx.x >> 4) * BM;
    const int wm = wave >> 1;                     // 0..1
    const int wn = wave & 1;                      // 0..1

    // staging: linear LDS dest (lane*16B); global source col pre-swizzled so
    // LDS[row][c'] holds global col c' ^ ((row&7)<<4)  (T2, rule #21)
    const int srow = lane >> 3;
    const int scol = 8 * ((lane & 7) ^ (lane >> 3));
    const int kbase = ksp * (KD / KSPLIT);

    f32x4 acc[4][4];
#pragma unroll
    for (int a = 0; a < 4; ++a)
#pragma unroll
        for (int b = 0; b < 4; ++b) acc[a][b] = (f32x4){0.f, 0.f, 0.f, 0.f};

    auto stage = [&](int kt) {
        const int buf = kt & 1;
        const int kk = kbase + kt * BK + scol;
#pragma unroll
        for (int c = 0; c < 4; ++c) {
            const int chunk = wave * 4 + c;       // 0..15 (8-row chunks)
            const unsigned short* ga = A + (size_t)(m0 + chunk * 8 + srow) * KD + kk;
            __builtin_amdgcn_global_load_lds(
                (const __attribute__((address_space(1))) unsigned int*)ga,
                (__attribute__((address_space(3))) unsigned int*)&As[buf][chunk * 512],
                16, 0, 0);
            const unsigned short* gb = W + (size_t)(n0 + chunk * 8 + srow) * KD + kk;
            __builtin_amdgcn_global_load_lds(
                (const __attribute__((address_space(1))) unsigned int*)gb,
                (__attribute__((address_space(3))) unsigned int*)&Bs[buf][chunk * 512],
                16, 0, 0);
        }
    };

    stage(0);

    const int arow = wm * 64 + (lane & 15);
    const int brow = wn * 64 + (lane & 15);
    const int xr   = lane & 7;
    const int kcol = lane >> 4;

    for (int kt = 0; kt < KT_PER; ++kt) {
        // own stage(kt) drained, then block-wide barrier: slot kt resident,
        // slot kt^1 fully consumed (reads retired before prior barrier).
        asm volatile("s_waitcnt vmcnt(0)" ::: "memory");
        __builtin_amdgcn_sched_barrier(0);
        __builtin_amdgcn_s_barrier();
        __builtin_amdgcn_sched_barrier(0);
        if (kt + 1 < KT_PER) stage(kt + 1);   // latency hides under this phase
        __builtin_amdgcn_sched_barrier(0);

        const int cur = kt & 1;
        __builtin_amdgcn_s_setprio(1);
#pragma unroll
        for (int ks = 0; ks < 2; ++ks) {
            const int slot = ((ks * 4 + kcol) ^ xr) * 8;   // swizzled k-slot
            bf16x8 af[4], bfr[4];
#pragma unroll
            for (int fm = 0; fm < 4; ++fm)
                af[fm] = *(const bf16x8*)&As[cur][(arow + fm * 16) * BK + slot];
#pragma unroll
            for (int fn = 0; fn < 4; ++fn)
                bfr[fn] = *(const bf16x8*)&Bs[cur][(brow + fn * 16) * BK + slot];
#pragma unroll
            for (int fm = 0; fm < 4; ++fm)
#pragma unroll
                for (int fn = 0; fn < 4; ++fn)
                    acc[fm][fn] = __builtin_amdgcn_mfma_f32_16x16x32_bf16(
                        af[fm], bfr[fn], acc[fm][fn], 0, 0, 0);
        }
        __builtin_amdgcn_s_setprio(0);
    }

    // epilogue: C/D layout col=lane&15, row=(lane>>4)*4+reg
    float* Cp = ksp ? P1 : C0;
    const int crow = (lane >> 4) * 4;
    const int ccol = lane & 15;
#pragma unroll
    for (int fm = 0; fm < 4; ++fm)
#pragma unroll
        for (int fn = 0; fn < 4; ++fn) {
            const int row = m0 + wm * 64 + fm * 16 + crow;
            const int col = n0 + wn * 64 + fn * 16 + ccol;
#pragma unroll
            for (int r = 0; r < 4; ++r)
                Cp[(size_t)(row + r) * DOUT + col] = acc[fm][fn][r];
        }
}

// ---------------------------------------------------------------------------
// X += P  (split-K reduce), float4 vectorized
// ---------------------------------------------------------------------------
__global__ __launch_bounds__(256) void reduce_add(
    const float* __restrict__ P, float* __restrict__ X) {
    const size_t i = ((size_t)blockIdx.x * 256 + threadIdx.x) * 4;
    f32x4 a = *(const f32x4*)(X + i);
    f32x4 b = *(const f32x4*)(P + i);
    a = a + b;
    *(f32x4*)(X + i) = a;
}

// ---------------------------------------------------------------------------
extern "C" void kernel_launch(void* const* d_in, const int* in_sizes, int n_in,
                              void* d_out, int out_size, void* d_ws, size_t ws_size,
                              hipStream_t stream) {
    const float* x        = (const float*)d_in[0];
    const float* base_w   = (const float*)d_in[1];
    const float* spline_w = (const float*)d_in[2];
    const float* scaler   = (const float*)d_in[3];
    const float* grid     = (const float*)d_in[4];
    float* out = (float*)d_out;

    char* ws = (char*)d_ws;
    unsigned short* Abf = (unsigned short*)ws;                         // 100,663,296 B
    unsigned short* Wbf = (unsigned short*)(ws + 100663296);           //  25,165,824 B
    float* xtmp = (float*)(ws + 100663296 + 25165824);                 //  16,777,216 B
    float* Part = (float*)(ws + 100663296 + 25165824 + 16777216);     //  16,777,216 B

    for (int layer = 0; layer < 2; ++layer) {
        const float* xin = (layer == 0) ? x : xtmp;
        float* xout      = (layer == 0) ? xtmp : out;
        build_W<<<4096, 256, 0, stream>>>(base_w + (size_t)layer * DOUT * DIN,
                                          spline_w + (size_t)layer * DOUT * DIN * NC,
                                          scaler + (size_t)layer * DOUT * DIN, Wbf);
        build_A<<<16384, 256, 0, stream>>>(xin, grid, Abf);
        gemm_kan<<<512, 256, 0, stream>>>(Abf, Wbf, xout, Part);
        reduce_add<<<BATCH * DOUT / 1024, 256, 0, stream>>>(Part, xout);
    }
}

// Round 6
// 333.491 us; speedup vs baseline: 1.7349x; 1.0713x over previous
//
#include <hip/hip_runtime.h>
#include <stdint.h>

#define BATCH 4096
#define DIN 1024
#define DOUT 1024
#define NC 11          // GRID_SIZE + SPLINE_ORDER
#define KD 12288       // DIN * (1 + NC)
#define NKNOTS 15      // GRID_SIZE + 2*SPLINE_ORDER + 1

typedef __bf16 bf16x8 __attribute__((ext_vector_type(8)));
typedef float f32x4 __attribute__((ext_vector_type(4)));

__device__ __forceinline__ unsigned short f2bf(float f) {
    unsigned int u = __float_as_uint(f);
    unsigned int r = (u + 0x7FFFu + ((u >> 16) & 1u)) >> 16;
    return (unsigned short)r;
}

// ---------------------------------------------------------------------------
// Build A[b, :] = [ silu(x[b,:]) (1024) | bsplines(silu(x[b,:])) (1024*11) ] in bf16
// ---------------------------------------------------------------------------
__global__ __launch_bounds__(256) void build_A(
    const float* __restrict__ x, const float* __restrict__ grid,
    unsigned short* __restrict__ A) {
    __shared__ __align__(16) unsigned short lbs[256 * NC];
    const int tid = threadIdx.x;
    const int b  = blockIdx.x >> 2;
    const int i0 = (blockIdx.x & 3) * 256;
    const int i  = i0 + tid;

    float g[NKNOTS];
#pragma unroll
    for (int j = 0; j < NKNOTS; ++j) g[j] = grid[j];

    const float xv = x[(size_t)b * DIN + i];
    const float s  = xv / (1.f + __expf(-xv));   // silu

    float bs[14];
#pragma unroll
    for (int c = 0; c < 14; ++c) bs[c] = (s >= g[c] && s < g[c + 1]) ? 1.f : 0.f;
#pragma unroll
    for (int k = 1; k <= 3; ++k) {
        const float inv = (k == 1) ? 4.f : (k == 2) ? 2.f : (4.f / 3.f);
#pragma unroll
        for (int c = 0; c < 14 - k; ++c) {
            float left  = (s - g[c]) * inv;
            float right = (g[c + k + 1] - s) * inv;
            bs[c] = left * bs[c] + right * bs[c + 1];
        }
    }

    A[(size_t)b * KD + i] = f2bf(s);
#pragma unroll
    for (int c = 0; c < NC; ++c) lbs[tid * NC + c] = f2bf(bs[c]);
    __syncthreads();

    const uint4* src = (const uint4*)lbs;
    uint4* dst = (uint4*)(A + (size_t)b * KD + DIN + (size_t)i0 * NC);
    for (int j = tid; j < 352; j += 256) dst[j] = src[j];
}

// ---------------------------------------------------------------------------
// Build W[o, :] = [ base_w[o,:] | spline_w[o,:,:]*scaler[o,:] ] in bf16
// ---------------------------------------------------------------------------
__global__ __launch_bounds__(256) void build_W(
    const float* __restrict__ base_w, const float* __restrict__ spline_w,
    const float* __restrict__ scaler, unsigned short* __restrict__ W) {
    __shared__ __align__(16) unsigned short lw[256 * NC];
    const int tid = threadIdx.x;
    const int o  = blockIdx.x >> 2;
    const int i0 = (blockIdx.x & 3) * 256;
    const int i  = i0 + tid;
    const size_t oi = (size_t)o * DIN + i;

    const float sc = scaler[oi];
    W[(size_t)o * KD + i] = f2bf(base_w[oi]);
    const float* sw = spline_w + oi * NC;
#pragma unroll
    for (int c = 0; c < NC; ++c) lw[tid * NC + c] = f2bf(sw[c] * sc);
    __syncthreads();

    const uint4* src = (const uint4*)lw;
    uint4* dst = (uint4*)(W + (size_t)o * KD + DIN + (size_t)i0 * NC);
    for (int j = tid; j < 352; j += 256) dst[j] = src[j];
}

// ---------------------------------------------------------------------------
// GEMM (split-K, runtime kspl 2 or 4): C = A[4096,12288] @ W[1024,12288]^T.
// 256x256 tile, BK=64, 512 threads = 8 waves (2m x 4n) of 128x64 each
// (acc 8x4). LDS 128KB dbuf -> 1 block/CU; 2 waves/SIMD.
// LDS bytes/FLOP: reads 192KB + writes 64KB per 8.4 MFLOP K-step -> cap ~62%
// (vs 50% for 64x64 wave tiles). Sync structure identical to proven R5
// kernel: vmcnt(0)+barrier at step top, stage(kt+1) right after (latency
// hides under ~2000cy compute phase), T2 XOR-swizzle, setprio around MFMA.
// ksp==0 writes C directly; ksp>=1 writes Part[ksp-1] (reduce adds later).
// ---------------------------------------------------------------------------
#define BM 256
#define BN 256
#define BK 64

__global__ __launch_bounds__(512, 2) void gemm_kan(
    const unsigned short* __restrict__ A,
    const unsigned short* __restrict__ W,
    float* __restrict__ C, float* __restrict__ Part,
    int kspl, int ktper) {
    __shared__ unsigned short As[2][BM * BK];   // 2 x 32KB
    __shared__ unsigned short Bs[2][BN * BK];   // 2 x 32KB (128KB total)

    const int tid  = threadIdx.x;
    const int wave = tid >> 6;
    const int lane = tid & 63;
    const int n0  = (blockIdx.x & 3) * BN;            // bid%4 == n-tile (XCD-local)
    const int ksp = (blockIdx.x >> 2) % kspl;
    const int m0  = (blockIdx.x / (4 * kspl)) * BM;
    const int wm = wave >> 2;                          // 0..1
    const int wn = wave & 3;                           // 0..3

    // staging: linear LDS dest (lane*16B); global source col pre-swizzled so
    // LDS[row][c'] holds global col c' ^ ((row&7)<<4)  (T2, rule #21)
    const int srow = lane >> 3;
    const int scol = 8 * ((lane & 7) ^ (lane >> 3));
    const int kbase = ksp * ktper * BK;

    f32x4 acc[8][4];
#pragma unroll
    for (int a = 0; a < 8; ++a)
#pragma unroll
        for (int b = 0; b < 4; ++b) acc[a][b] = (f32x4){0.f, 0.f, 0.f, 0.f};

    auto stage = [&](int kt) {
        const int buf = kt & 1;
        const int kk = kbase + kt * BK + scol;
#pragma unroll
        for (int c = 0; c < 4; ++c) {
            const int chunk = wave * 4 + c;            // 0..31 (8-row chunks)
            const unsigned short* ga = A + (size_t)(m0 + chunk * 8 + srow) * KD + kk;
            __builtin_amdgcn_global_load_lds(
                (const __attribute__((address_space(1))) unsigned int*)ga,
                (__attribute__((address_space(3))) unsigned int*)&As[buf][chunk * 512],
                16, 0, 0);
            const unsigned short* gb = W + (size_t)(n0 + chunk * 8 + srow) * KD + kk;
            __builtin_amdgcn_global_load_lds(
                (const __attribute__((address_space(1))) unsigned int*)gb,
                (__attribute__((address_space(3))) unsigned int*)&Bs[buf][chunk * 512],
                16, 0, 0);
        }
    };

    stage(0);

    const int arow = wm * 128 + (lane & 15);
    const int brow = wn * 64 + (lane & 15);
    const int xr   = lane & 7;
    const int kcol = lane >> 4;

    for (int kt = 0; kt < ktper; ++kt) {
        // stage(kt) drained (issued a full compute phase ago), then barrier:
        // slot kt resident, slot kt^1 fully consumed by all waves.
        asm volatile("s_waitcnt vmcnt(0)" ::: "memory");
        __builtin_amdgcn_sched_barrier(0);
        __builtin_amdgcn_s_barrier();
        __builtin_amdgcn_sched_barrier(0);
        if (kt + 1 < ktper) stage(kt + 1);   // latency hides under this phase
        __builtin_amdgcn_sched_barrier(0);

        const int cur = kt & 1;
        __builtin_amdgcn_s_setprio(1);
#pragma unroll
        for (int ks = 0; ks < 2; ++ks) {
            const int slot = ((ks * 4 + kcol) ^ xr) * 8;   // swizzled k-slot
            bf16x8 af[8], bfr[4];
#pragma unroll
            for (int fm = 0; fm < 8; ++fm)
                af[fm] = *(const bf16x8*)&As[cur][(arow + fm * 16) * BK + slot];
#pragma unroll
            for (int fn = 0; fn < 4; ++fn)
                bfr[fn] = *(const bf16x8*)&Bs[cur][(brow + fn * 16) * BK + slot];
#pragma unroll
            for (int fm = 0; fm < 8; ++fm)
#pragma unroll
                for (int fn = 0; fn < 4; ++fn)
                    acc[fm][fn] = __builtin_amdgcn_mfma_f32_16x16x32_bf16(
                        af[fm], bfr[fn], acc[fm][fn], 0, 0, 0);
        }
        __builtin_amdgcn_s_setprio(0);
    }

    // epilogue: C/D layout col=lane&15, row=(lane>>4)*4+reg
    float* Cp = (ksp == 0) ? C : (Part + (size_t)(ksp - 1) * BATCH * DOUT);
    const int crow = (lane >> 4) * 4;
    const int ccol = lane & 15;
#pragma unroll
    for (int fm = 0; fm < 8; ++fm)
#pragma unroll
        for (int fn = 0; fn < 4; ++fn) {
            const int row = m0 + wm * 128 + fm * 16 + crow;
            const int col = n0 + wn * 64 + fn * 16 + ccol;
#pragma unroll
            for (int r = 0; r < 4; ++r)
                Cp[(size_t)(row + r) * DOUT + col] = acc[fm][fn][r];
        }
}

// ---------------------------------------------------------------------------
// X += sum of np partial slices, float4 vectorized
// ---------------------------------------------------------------------------
__global__ __launch_bounds__(256) void reduce_add(
    const float* __restrict__ P, float* __restrict__ X, int np) {
    const size_t i = ((size_t)blockIdx.x * 256 + threadIdx.x) * 4;
    f32x4 a = *(const f32x4*)(X + i);
    for (int p = 0; p < np; ++p)
        a = a + *(const f32x4*)(P + (size_t)p * BATCH * DOUT + i);
    *(f32x4*)(X + i) = a;
}

// ---------------------------------------------------------------------------
extern "C" void kernel_launch(void* const* d_in, const int* in_sizes, int n_in,
                              void* d_out, int out_size, void* d_ws, size_t ws_size,
                              hipStream_t stream) {
    const float* x        = (const float*)d_in[0];
    const float* base_w   = (const float*)d_in[1];
    const float* spline_w = (const float*)d_in[2];
    const float* scaler   = (const float*)d_in[3];
    const float* grid     = (const float*)d_in[4];
    float* out = (float*)d_out;

    char* ws = (char*)d_ws;
    unsigned short* Abf = (unsigned short*)ws;                       // 100,663,296 B
    unsigned short* Wbf = (unsigned short*)(ws + 100663296);         //  25,165,824 B
    float* xtmp = (float*)(ws + 100663296 + 25165824);               //  16,777,216 B
    float* Part = (float*)(ws + 100663296 + 25165824 + 16777216);    // up to 3x16.8MB

    // kspl=4 needs 3 partial buffers (total ws 193MB); fall back if short.
    const size_t base_need = 100663296u + 25165824u + 16777216u;
    const int kspl = (ws_size >= base_need + 3u * 16777216u) ? 4 : 2;
    const int ktper = (KD / BK) / kspl;

    for (int layer = 0; layer < 2; ++layer) {
        const float* xin = (layer == 0) ? x : xtmp;
        float* xout      = (layer == 0) ? xtmp : out;
        build_W<<<4096, 256, 0, stream>>>(base_w + (size_t)layer * DOUT * DIN,
                                          spline_w + (size_t)layer * DOUT * DIN * NC,
                                          scaler + (size_t)layer * DOUT * DIN, Wbf);
        build_A<<<16384, 256, 0, stream>>>(xin, grid, Abf);
        gemm_kan<<<64 * kspl, 512, 0, stream>>>(Abf, Wbf, xout, Part, kspl, ktper);
        reduce_add<<<BATCH * DOUT / 1024, 256, 0, stream>>>(Part, xout, kspl - 1);
    }
}